// Round 13
// baseline (378.546 us; speedup 1.0000x reference)
//
#include <hip/hip_runtime.h>
#include <math.h>

#define N_NODES 100000
#define NBUK 256
#define BNODES ((N_NODES + NBUK - 1) / NBUK)   // 391 nodes per bucket
#define BCAP 10240                             // per-bucket stream capacity (mean 6250)
#define CHUNK 2048                             // edges per chunk (782 blocks for E=1.6M)
#define NGRP 8                                 // scan groups

__device__ __forceinline__ unsigned bf16rne(float f) {
    unsigned u = __float_as_uint(f);
    return (u + 0x7FFFu + ((u >> 16) & 1u)) >> 16;
}

// ---------------- CSR build step 1: per-chunk 256-bucket histograms (no global atomics) ----------------
__global__ __launch_bounds__(256) void hist1_kernel(const int* __restrict__ src,
                                                    const int* __restrict__ dst,
                                                    int* __restrict__ hist_d,
                                                    int* __restrict__ hist_s, int E) {
    __shared__ int hd[NBUK];
    __shared__ int hs[NBUK];
    const int t = threadIdx.x;
    const int cbase = blockIdx.x * CHUNK;
    const int csize = min(CHUNK, E - cbase);
    hd[t] = 0;
    hs[t] = 0;
    __syncthreads();
    for (int i = t; i < csize; i += 256) {
        int d = dst[cbase + i];
        int s = src[cbase + i];
        atomicAdd(&hd[d / BNODES], 1);
        atomicAdd(&hs[s / BNODES], 1);
    }
    __syncthreads();
    hist_d[(size_t)blockIdx.x * NBUK + t] = hd[t];
    hist_s[(size_t)blockIdx.x * NBUK + t] = hs[t];
}

// ---------------- step 2: in-place local scan per (side, group); emits group partials ----------------
__global__ void local_scan_kernel(int* __restrict__ hist_d, int* __restrict__ hist_s,
                                  int* __restrict__ part_d, int* __restrict__ part_s,
                                  int nch, int cpg) {
    const int t = threadIdx.x;
    const int side = blockIdx.x & 1;
    const int g = blockIdx.x >> 1;
    int* hist = side ? hist_s : hist_d;
    int* part = side ? part_s : part_d;
    int c0 = g * cpg;
    int c1 = min(nch, c0 + cpg);
    int run = 0;
    for (int c = c0; c < c1; ++c) {
        int v = hist[(size_t)c * NBUK + t];
        hist[(size_t)c * NBUK + t] = run;   // local (within-group) base
        run += v;
    }
    part[g * NBUK + t] = run;
}

// ---------------- step 3: scan group partials -> group offsets + exact bucket totals ----------------
__global__ void group_scan_kernel(int* __restrict__ part_d, int* __restrict__ part_s,
                                  int* __restrict__ bcnt_d, int* __restrict__ bcnt_s) {
    const int t = threadIdx.x;
    int* part = blockIdx.x ? part_s : part_d;
    int* bcnt = blockIdx.x ? bcnt_s : bcnt_d;
    int run = 0;
#pragma unroll
    for (int g = 0; g < NGRP; ++g) {
        int v = part[g * NBUK + t];
        part[g * NBUK + t] = run;           // exclusive group offset
        run += v;
    }
    bcnt[t] = run;
}

// ---------------- bucket base: exclusive scan of per-bucket edge counts ----------------
__global__ void bucket_base_kernel(const int* __restrict__ bcnt_d, int* __restrict__ csr_base,
                                   int* __restrict__ row_start) {
    __shared__ int lds[NBUK];
    int t = threadIdx.x;
    int v = min(bcnt_d[t], BCAP);
    lds[t] = v;
    __syncthreads();
    for (int off = 1; off < NBUK; off <<= 1) {
        int y = (t >= off) ? lds[t - off] : 0;
        __syncthreads();
        lds[t] += y;
        __syncthreads();
    }
    csr_base[t] = lds[t] - v;  // exclusive
    if (t == NBUK - 1) row_start[N_NODES] = lds[NBUK - 1];
}

// ---------------- step 4: scatter into bucket streams (LDS cursors, zero global atomics) ----------------
__global__ __launch_bounds__(256) void scatter_ms_kernel(const int* __restrict__ src,
                                                         const int* __restrict__ dst,
                                                         const int* __restrict__ hist_d,
                                                         const int* __restrict__ hist_s,
                                                         const int* __restrict__ part_d,
                                                         const int* __restrict__ part_s,
                                                         unsigned int* __restrict__ dstream,
                                                         unsigned short* __restrict__ sstream,
                                                         int E, int cpg) {
    __shared__ int cd[NBUK];
    __shared__ int cs[NBUK];
    const int t = threadIdx.x;
    const int c = blockIdx.x;
    const int g = c / cpg;
    const int cbase = c * CHUNK;
    const int csize = min(CHUNK, E - cbase);
    cd[t] = hist_d[(size_t)c * NBUK + t] + part_d[g * NBUK + t];
    cs[t] = hist_s[(size_t)c * NBUK + t] + part_s[g * NBUK + t];
    __syncthreads();
    for (int i = t; i < csize; i += 256) {
        int d = dst[cbase + i];
        int s = src[cbase + i];
        int bd = d / BNODES;
        int bs = s / BNODES;
        int slot = atomicAdd(&cd[bd], 1);
        if (slot < BCAP)
            dstream[(size_t)bd * BCAP + slot] = ((unsigned)s << 9) | (unsigned)(d - bd * BNODES);
        int slot2 = atomicAdd(&cs[bs], 1);
        if (slot2 < BCAP)
            sstream[(size_t)bs * BCAP + slot2] = (unsigned short)(s - bs * BNODES);
    }
}

// ---------------- pass 2 (dst): per-bucket node hist + scan + local scatter ----------------
__global__ __launch_bounds__(256) void pass2_dst_kernel(const unsigned int* __restrict__ dstream,
                                                        const int* __restrict__ bcnt_d,
                                                        const int* __restrict__ csr_base,
                                                        float* __restrict__ isi,
                                                        int* __restrict__ row_start,
                                                        int* __restrict__ csr_src) {
    __shared__ int cnt[512];
    __shared__ int pfx[512];
    __shared__ int wsum[256];
    const int b = blockIdx.x;
    const int t = threadIdx.x;
    const int m = min(bcnt_d[b], BCAP);
    const int base = csr_base[b];
    const int nbeg = b * BNODES;
    const int nn = min(BNODES, N_NODES - nbeg);
    const unsigned int* eb = dstream + (size_t)b * BCAP;

    cnt[t] = 0;
    cnt[t + 256] = 0;
    __syncthreads();
    for (int i = t; i < m; i += 256) atomicAdd(&cnt[eb[i] & 511], 1);
    __syncthreads();
    int c0 = cnt[2 * t], c1 = cnt[2 * t + 1];
    int s = c0 + c1;
    wsum[t] = s;
    __syncthreads();
    for (int off = 1; off < 256; off <<= 1) {
        int y = (t >= off) ? wsum[t - off] : 0;
        __syncthreads();
        wsum[t] += y;
        __syncthreads();
    }
    int excl = wsum[t] - s;
    pfx[2 * t] = excl;
    pfx[2 * t + 1] = excl + c0;
    __syncthreads();
    for (int j = t; j < nn; j += 256) {
        isi[nbeg + j] = rsqrtf(fmaxf((float)cnt[j], 1.0f));
        row_start[nbeg + j] = base + pfx[j];
    }
    __syncthreads();
    cnt[t] = pfx[t];
    cnt[t + 256] = pfx[t + 256];
    __syncthreads();
    for (int i = t; i < m; i += 256) {
        unsigned int p = eb[i];
        int dl = p & 511;
        int sv = p >> 9;
        int pos = atomicAdd(&cnt[dl], 1);
        csr_src[base + pos] = sv;
    }
}

// ---------------- pass 2 (src): per-bucket hist -> iso ----------------
__global__ __launch_bounds__(256) void pass2_src_kernel(const unsigned short* __restrict__ sstream,
                                                        const int* __restrict__ bcnt_s,
                                                        float* __restrict__ iso) {
    __shared__ int cnt[512];
    const int b = blockIdx.x;
    const int t = threadIdx.x;
    const int m = min(bcnt_s[b], BCAP);
    const int nbeg = b * BNODES;
    const int nn = min(BNODES, N_NODES - nbeg);
    const unsigned short* eb = sstream + (size_t)b * BCAP;

    cnt[t] = 0;
    cnt[t + 256] = 0;
    __syncthreads();
    for (int i = t; i < m; i += 256) atomicAdd(&cnt[eb[i]], 1);
    __syncthreads();
    for (int j = t; j < nn; j += 256) iso[nbeg + j] = rsqrtf(fmaxf((float)cnt[j], 1.0f));
}

// ---------------- register-blocked GEMM: out = diag(iso) * (x @ W) ----------------
// BF16OUT: pack output rows as 32 uints (bf16 pairs) instead of 64 floats.
template <int DOUT, bool BF16OUT>
__global__ __launch_bounds__(256) void gemm_scale_kernel(const float* __restrict__ x,
                                                         const float* __restrict__ W,
                                                         const float* __restrict__ iso,
                                                         void* __restrict__ out_, int n) {
    constexpr int TC = DOUT / 4;
    constexpr int TR = 256 / TC;
    constexpr int ROWS = TR * 4;

    __shared__ float Xs[64 * ROWS];
    __shared__ float Ws[64 * DOUT];

    const int t = threadIdx.x;
    const int row_base = blockIdx.x * ROWS;

    {
        const float4* Wg = reinterpret_cast<const float4*>(W);
        float4* Ws4 = reinterpret_cast<float4*>(Ws);
        for (int i = t; i < 64 * TC; i += 256) Ws4[i] = Wg[i];
    }
    {
        const float4* xg = reinterpret_cast<const float4*>(x);
#pragma unroll
        for (int it = 0; it < ROWS / 16; ++it) {
            int f = t + it * 256;
            int r = f >> 4;
            int kq = f & 15;
            int row = row_base + r;
            int rcl = row < n ? row : n - 1;
            float4 v = xg[(size_t)rcl * 16 + kq];
            int rp = r ^ ((kq & 7) << 2);
            Xs[(kq * 4 + 0) * ROWS + rp] = v.x;
            Xs[(kq * 4 + 1) * ROWS + rp] = v.y;
            Xs[(kq * 4 + 2) * ROWS + rp] = v.z;
            Xs[(kq * 4 + 3) * ROWS + rp] = v.w;
        }
    }
    __syncthreads();

    const int tc = t % TC;
    const int tr = t / TC;

    float acc[4][4];
#pragma unroll
    for (int i = 0; i < 4; ++i)
#pragma unroll
        for (int j = 0; j < 4; ++j) acc[i][j] = 0.0f;

    const float4* Xs4 = reinterpret_cast<const float4*>(Xs);
    const float4* Ws4 = reinterpret_cast<const float4*>(Ws);

#pragma unroll 8
    for (int k = 0; k < 64; ++k) {
        float4 a = Xs4[k * (ROWS / 4) + (tr ^ ((k >> 2) & 7))];
        float4 b = Ws4[k * TC + tc];
        acc[0][0] += a.x * b.x; acc[0][1] += a.x * b.y; acc[0][2] += a.x * b.z; acc[0][3] += a.x * b.w;
        acc[1][0] += a.y * b.x; acc[1][1] += a.y * b.y; acc[1][2] += a.y * b.z; acc[1][3] += a.y * b.w;
        acc[2][0] += a.z * b.x; acc[2][1] += a.z * b.y; acc[2][2] += a.z * b.z; acc[2][3] += a.z * b.w;
        acc[3][0] += a.w * b.x; acc[3][1] += a.w * b.y; acc[3][2] += a.w * b.z; acc[3][3] += a.w * b.w;
    }

#pragma unroll
    for (int i = 0; i < 4; ++i) {
        int row = row_base + tr * 4 + i;
        if (row < n) {
            float sc = iso[row];
            if (BF16OUT) {
                unsigned b0 = bf16rne(acc[i][0] * sc);
                unsigned b1 = bf16rne(acc[i][1] * sc);
                unsigned b2 = bf16rne(acc[i][2] * sc);
                unsigned b3 = bf16rne(acc[i][3] * sc);
                uint2 o;
                o.x = (b1 << 16) | b0;
                o.y = (b3 << 16) | b2;
                // row = TC uint2 (16 for DOUT=64); thread tc owns uint2 slot tc.
                reinterpret_cast<uint2*>(out_)[(size_t)row * TC + tc] = o;
            } else {
                float4 o;
                o.x = acc[i][0] * sc;
                o.y = acc[i][1] * sc;
                o.z = acc[i][2] * sc;
                o.w = acc[i][3] * sc;
                reinterpret_cast<float4*>(out_)[(size_t)row * TC + tc] = o;
            }
        }
    }
}

// ---------------- bf16 gather (D=64): 32-lane groups, each lane owns 2 columns ----------------
// MODE: 0 = tanh, 1 = relu. Output fp32 [n,64].
template <int MODE>
__global__ __launch_bounds__(256) void gather64_bf16_kernel(const unsigned int* __restrict__ h2,
                                                            const int* __restrict__ csr_src,
                                                            const int* __restrict__ row_start,
                                                            const float* __restrict__ isi,
                                                            const float* __restrict__ b,
                                                            float* __restrict__ out, int n) {
    int g = threadIdx.x >> 5;        // 8 node-groups per block
    int j = threadIdx.x & 31;        // uint column (covers bf16 cols 2j, 2j+1)
    int node = blockIdx.x * 8 + g;
    if (node >= n) return;

    int beg = row_start[node];
    int end = row_start[node + 1];
    float acc0 = 0.0f, acc1 = 0.0f;
    int e = beg;
    for (; e + 4 <= end; e += 4) {
        int s0 = csr_src[e + 0];
        int s1 = csr_src[e + 1];
        int s2 = csr_src[e + 2];
        int s3 = csr_src[e + 3];
        unsigned p0 = h2[(size_t)s0 * 32 + j];
        unsigned p1 = h2[(size_t)s1 * 32 + j];
        unsigned p2 = h2[(size_t)s2 * 32 + j];
        unsigned p3 = h2[(size_t)s3 * 32 + j];
        acc0 += __uint_as_float(p0 << 16) + __uint_as_float(p1 << 16) +
                __uint_as_float(p2 << 16) + __uint_as_float(p3 << 16);
        acc1 += __uint_as_float(p0 & 0xFFFF0000u) + __uint_as_float(p1 & 0xFFFF0000u) +
                __uint_as_float(p2 & 0xFFFF0000u) + __uint_as_float(p3 & 0xFFFF0000u);
    }
    for (; e < end; ++e) {
        unsigned p = h2[(size_t)csr_src[e] * 32 + j];
        acc0 += __uint_as_float(p << 16);
        acc1 += __uint_as_float(p & 0xFFFF0000u);
    }

    float sc = isi[node];
    float v0 = acc0 * sc + b[2 * j];
    float v1 = acc1 * sc + b[2 * j + 1];
    if (MODE == 0) {
        v0 = tanhf(v0);
        v1 = tanhf(v1);
    } else {
        v0 = fmaxf(v0, 0.0f);
        v1 = fmaxf(v1, 0.0f);
    }
    float2 o = make_float2(v0, v1);
    reinterpret_cast<float2*>(out)[(size_t)node * 32 + j] = o;
}

// ---------------- fp32 gather (layer 3, D=32) + reparameterization epilogue ----------------
__global__ void gather32_final_kernel(const float* __restrict__ h, const int* __restrict__ csr_src,
                                      const int* __restrict__ row_start, const float* __restrict__ isi,
                                      const float* __restrict__ b, const float* __restrict__ eps,
                                      float* __restrict__ out, int n) {
    const int D = 32;
    int g = threadIdx.x / D;
    int j = threadIdx.x % D;
    int node = blockIdx.x * 8 + g;
    if (node >= n) return;

    int beg = row_start[node];
    int end = row_start[node + 1];
    float acc = 0.0f;
    int e = beg;
    for (; e + 4 <= end; e += 4) {
        int s0 = csr_src[e + 0];
        int s1 = csr_src[e + 1];
        int s2 = csr_src[e + 2];
        int s3 = csr_src[e + 3];
        acc += h[(long long)s0 * D + j] + h[(long long)s1 * D + j] +
               h[(long long)s2 * D + j] + h[(long long)s3 * D + j];
    }
    for (; e < end; ++e) acc += h[(long long)csr_src[e] * D + j];

    float v = acc * isi[node] + b[j];
    const int total = N_NODES * 32;
    int i = node * 32 + j;
    out[i] = v + expf(v) * eps[i];  // z_adj
    out[total + i] = v;             // z_log_std
    out[2 * total + i] = v;         // z_mean
}

static inline size_t align_up(size_t x, size_t a) { return (x + a - 1) & ~(a - 1); }

extern "C" void kernel_launch(void* const* d_in, const int* in_sizes, int n_in,
                              void* d_out, int out_size, void* d_ws, size_t ws_size,
                              hipStream_t stream) {
    const float* feat = (const float*)d_in[0];   // [N,64]
    const int* src = (const int*)d_in[1];        // [E]
    const int* dst = (const int*)d_in[2];        // [E]
    const float* eps = (const float*)d_in[3];    // [N,32]
    const float* W1 = (const float*)d_in[4];     // [64,64]
    const float* b1 = (const float*)d_in[5];     // [64]
    const float* W2 = (const float*)d_in[6];     // [64,64]
    const float* b2 = (const float*)d_in[7];     // [64]
    const float* Wm = (const float*)d_in[8];     // [64,32]
    const float* bm = (const float*)d_in[9];     // [32]

    const int N = N_NODES;
    const int E = in_sizes[1];
    float* out = (float*)d_out;

    // workspace carve-up
    char* ws = (char*)d_ws;
    size_t off = 0;
    float* iso     = (float*)(ws + off); off = align_up(off + (size_t)N * 4, 256);
    float* isi     = (float*)(ws + off); off = align_up(off + (size_t)N * 4, 256);
    int* row_start = (int*)(ws + off); off = align_up(off + (size_t)(N + 1) * 4, 256);
    int* csr_base  = (int*)(ws + off); off = align_up(off + (size_t)NBUK * 4, 256);
    int* bcnt_d    = (int*)(ws + off); off = align_up(off + (size_t)NBUK * 4, 256);
    int* bcnt_s    = (int*)(ws + off); off = align_up(off + (size_t)NBUK * 4, 256);
    int* csr_src   = (int*)(ws + off); off = align_up(off + (size_t)E * 4, 256);
    float* bufA    = (float*)(ws + off); off = align_up(off + (size_t)N * 64 * 4, 256);  // gemm out / streams alias
    float* bufH    = (float*)(ws + off); off = align_up(off + (size_t)N * 64 * 4, 256);  // h1/h2 / hist alias
    (void)ws_size;
    // streams alias bufA (dead before first gemm writes it)
    unsigned int* dstream = (unsigned int*)bufA;
    unsigned short* sstream = (unsigned short*)((char*)bufA + (size_t)NBUK * BCAP * 4);
    unsigned int* bufA_bf16 = (unsigned int*)bufA;  // [N,32] packed bf16 pairs
    // hist/part arrays alias bufH (dead before layer-1 gather writes it)
    const int nch = (E + CHUNK - 1) / CHUNK;         // 782 for E=1.6M
    const int cpg = (nch + NGRP - 1) / NGRP;         // chunks per group
    int* hist_d = (int*)bufH;
    int* hist_s = hist_d + (size_t)nch * NBUK;
    int* part_d = hist_s + (size_t)nch * NBUK;
    int* part_s = part_d + (size_t)NGRP * NBUK;

    const int B = 256;

    // ---- CSR build: fully atomic-free multisplit ----
    hist1_kernel<<<nch, B, 0, stream>>>(src, dst, hist_d, hist_s, E);
    local_scan_kernel<<<2 * NGRP, B, 0, stream>>>(hist_d, hist_s, part_d, part_s, nch, cpg);
    group_scan_kernel<<<2, B, 0, stream>>>(part_d, part_s, bcnt_d, bcnt_s);
    bucket_base_kernel<<<1, NBUK, 0, stream>>>(bcnt_d, csr_base, row_start);
    scatter_ms_kernel<<<nch, B, 0, stream>>>(src, dst, hist_d, hist_s, part_d, part_s,
                                             dstream, sstream, E, cpg);
    pass2_dst_kernel<<<NBUK, B, 0, stream>>>(dstream, bcnt_d, csr_base, isi, row_start, csr_src);
    pass2_src_kernel<<<NBUK, B, 0, stream>>>(sstream, bcnt_s, iso);

    // ---- layer 1: h1 = tanh(conv(feat, W1, b1)) ---- (bf16 staging)
    gemm_scale_kernel<64, true><<<(N + 63) / 64, B, 0, stream>>>(feat, W1, iso, bufA_bf16, N);
    gather64_bf16_kernel<0><<<(N + 7) / 8, B, 0, stream>>>(bufA_bf16, csr_src, row_start, isi, b1, bufH, N);

    // ---- layer 2: h2 = relu(conv(h1, W2, b2)) ---- (bf16 staging)
    gemm_scale_kernel<64, true><<<(N + 63) / 64, B, 0, stream>>>(bufH, W2, iso, bufA_bf16, N);
    gather64_bf16_kernel<1><<<(N + 7) / 8, B, 0, stream>>>(bufA_bf16, csr_src, row_start, isi, b2, bufH, N);

    // ---- layer 3: z = conv(h2, Wm, bm); fp32 end-to-end (feeds exp) ----
    gemm_scale_kernel<32, false><<<(N + 127) / 128, B, 0, stream>>>(bufH, Wm, iso, bufA, N);
    gather32_final_kernel<<<(N + 7) / 8, B, 0, stream>>>(bufA, csr_src, row_start, isi, bm, eps, out, N);
}